// Round 4
// baseline (330.559 us; speedup 1.0000x reference)
//
#include <hip/hip_runtime.h>

#define NPTS   64
#define NCOLS  500000
#define NANG   2016        // 64*63/2
#define NFULL  7812        // NCOLS / 64 (32-col tail = 2 extra 16-col waves)
#define TPB    1024        // 16 waves/block
#define BLOCKS 512         // 2 blocks/CU * 256 CUs -> 32 waves/CU resident

typedef __attribute__((ext_vector_type(8))) short bf16x8;
typedef __attribute__((ext_vector_type(4))) float f32x4;

static __device__ __forceinline__ short f2bf(float f) {
    union { float f; unsigned u; } uf; uf.f = f;
    unsigned u = uf.u;
    unsigned r = (u + 0x7fffu + ((u >> 16) & 1u)) >> 16;  // RNE bf16
    return (short)r;
}

// rotations before round i (iTop = i): S(i) = 63i - i(i-1)/2
static __host__ __device__ constexpr int rotS(int i) { return 63 * i - i * (i - 1) / 2; }

// ---------------------------------------------------------------------------
// ROLLED Givens chain on an LDS-resident 64x64 P (thread = column).
// t = P[i][lane] carried in a register; b = P[ib][lane] round-trips LDS
// (stride-1 across lanes -> 2-way bank alias = free). unroll 8 so eight
// independent ds_reads issue per waitcnt batch; the only serial dependence
// is the 1-FMA t-chain.
// ---------------------------------------------------------------------------
__device__ __forceinline__ void chain_rolled(const float2* __restrict__ csn,
                                             float* __restrict__ P,
                                             int lane, int I0, int I1) {
    for (int r = 0; r < 64; ++r) P[r * 64 + lane] = (r == lane) ? 1.0f : 0.0f;
    int k = 0;
#pragma unroll 1
    for (int i = I0; i < I1; ++i) {
        float t = P[i * 64 + lane];
#pragma unroll 8
        for (int ib = i + 1; ib < 64; ++ib, ++k) {
            float2 cs = csn[k];                    // (cos, sin), LDS broadcast
            float b = P[ib * 64 + lane];
            P[ib * 64 + lane] = cs.y * t + cs.x * b;   // vb' = s*vt + c*vb (old vt)
            t = cs.x * t - cs.y * b;                   // vt' = c*vt - s*vb
        }
        P[i * 64 + lane] = t;
    }
}

// ---------------------------------------------------------------------------
// Single fused kernel, 1024 thr (16 waves), 65280 B LDS, VGPR<=64:
//   phase 0: cos/sin of 2016 angles -> LDS
//   phase 1: P0 = rounds [0,12) | P1 = [12,26) | P2 = [26,63)   (waves 0..2,
//            690/623/703 rots, rolled chains in parallel)
//   phase 2: Q0 = P1*P0 -> P0 slot ; M = diag(mus)*P2*Q0 -> P1 slot
//            (two in-LDS 64^3 matmuls, all 16 waves, 4 rows each)
//   phase 3: afrag <- bf16(M); ONE stripe per wave (8192 waves >= 7812)
// ---------------------------------------------------------------------------
__global__ __launch_bounds__(TPB, 8) void fused_ortho(const float* __restrict__ X,
                                                      const float* __restrict__ angles,
                                                      const float* __restrict__ mus,
                                                      float* __restrict__ out) {
    __shared__ __align__(16) float sm[4032 + 3 * 4096];   // 65280 B
    const int tid  = threadIdx.x;
    const int lane = tid & 63;
    const int wave = __builtin_amdgcn_readfirstlane(tid >> 6);

    // ---- phase 0: stage cos/sin ----
    float2* csn = (float2*)sm;                  // 2016 float2 = 16128 B
    for (int t = tid; t < NANG; t += TPB) {
        float s, c;
        sincosf(angles[t], &s, &c);
        csn[t] = make_float2(c, s);
    }
    __syncthreads();

    float* P0 = sm + 4032;
    float* P1 = sm + 8128;
    float* P2 = sm + 12224;

    // ---- phase 1: three parallel rolled chains ----
    if (wave == 0)      chain_rolled(csn,            P0, lane,  0, 12);  // 690
    else if (wave == 1) chain_rolled(csn + rotS(12), P1, lane, 12, 26);  // 623
    else if (wave == 2) chain_rolled(csn + rotS(26), P2, lane, 26, 63);  // 703
    __syncthreads();

    // ---- phase 2a: Q0 = P1 * P0 -> P0 slot (wave owns rows wave*4..+3) ----
    {
        const int row0 = wave * 4;
        float acc[4] = {0.f, 0.f, 0.f, 0.f};
#pragma unroll 4
        for (int k0 = 0; k0 < 64; k0 += 4) {
            float lo0 = P0[(k0 + 0) * 64 + lane];
            float lo1 = P0[(k0 + 1) * 64 + lane];
            float lo2 = P0[(k0 + 2) * 64 + lane];
            float lo3 = P0[(k0 + 3) * 64 + lane];
#pragma unroll
            for (int r = 0; r < 4; ++r) {
                const f32x4 h = *(const f32x4*)&P1[(row0 + r) * 64 + k0]; // broadcast
                acc[r] = fmaf(h[0], lo0, acc[r]);
                acc[r] = fmaf(h[1], lo1, acc[r]);
                acc[r] = fmaf(h[2], lo2, acc[r]);
                acc[r] = fmaf(h[3], lo3, acc[r]);
            }
        }
        __syncthreads();               // all P0 reads done
#pragma unroll
        for (int r = 0; r < 4; ++r) P0[(row0 + r) * 64 + lane] = acc[r];
    }
    __syncthreads();

    // ---- phase 2b: M = diag(mus) * P2 * Q0 -> P1 slot ----
    {
        const int row0 = wave * 4;
        float acc[4] = {0.f, 0.f, 0.f, 0.f};
#pragma unroll 4
        for (int k0 = 0; k0 < 64; k0 += 4) {
            float lo0 = P0[(k0 + 0) * 64 + lane];
            float lo1 = P0[(k0 + 1) * 64 + lane];
            float lo2 = P0[(k0 + 2) * 64 + lane];
            float lo3 = P0[(k0 + 3) * 64 + lane];
#pragma unroll
            for (int r = 0; r < 4; ++r) {
                const f32x4 h = *(const f32x4*)&P2[(row0 + r) * 64 + k0]; // broadcast
                acc[r] = fmaf(h[0], lo0, acc[r]);
                acc[r] = fmaf(h[1], lo1, acc[r]);
                acc[r] = fmaf(h[2], lo2, acc[r]);
                acc[r] = fmaf(h[3], lo3, acc[r]);
            }
        }
        // writes go to P1 (not read here) -> no barrier needed before store
#pragma unroll
        for (int r = 0; r < 4; ++r)
            P1[(row0 + r) * 64 + lane] = acc[r] * mus[row0 + r];
    }
    __syncthreads();

    // ---- phase 3: afrag from M (P1 slot), then one stripe per wave ----
    const int laneN = lane & 15;
    const int quad  = lane >> 4;

    bf16x8 afrag[4][2];
#pragma unroll
    for (int t = 0; t < 4; ++t) {
#pragma unroll
        for (int q = 0; q < 2; ++q) {
            const float* src = P1 + (t * 16 + laneN) * 64 + q * 32 + quad * 8;
            bf16x8 f;
#pragma unroll
            for (int j = 0; j < 8; ++j) f[j] = f2bf(src[j]);
            afrag[t][q] = f;
        }
    }

    const int gw = blockIdx.x * 16 + wave;   // [0, 8192)

    if (gw < NFULL) {
        const long col0 = (long)gw * 64 + 4 * laneN;
        const float* xb = X + col0;

        bf16x8 bfrag[4][2];
#pragma unroll
        for (int q = 0; q < 2; ++q) {
#pragma unroll
            for (int j = 0; j < 8; ++j) {
                const int kk = q * 32 + quad * 8 + j;
                f32x4 v = *(const f32x4*)(xb + (long)kk * NCOLS);
#pragma unroll
                for (int u = 0; u < 4; ++u)
                    bfrag[u][q][j] = f2bf(v[u]);
            }
        }

#pragma unroll
        for (int t = 0; t < 4; ++t) {
            f32x4 acc[4];
#pragma unroll
            for (int u = 0; u < 4; ++u) {
                f32x4 a = {0.f, 0.f, 0.f, 0.f};
                a = __builtin_amdgcn_mfma_f32_16x16x32_bf16(afrag[t][0], bfrag[u][0], a, 0, 0, 0);
                a = __builtin_amdgcn_mfma_f32_16x16x32_bf16(afrag[t][1], bfrag[u][1], a, 0, 0, 0);
                acc[u] = a;
            }
#pragma unroll
            for (int rr = 0; rr < 4; ++rr) {
                const int row = t * 16 + quad * 4 + rr;
                f32x4 o = { acc[0][rr], acc[1][rr], acc[2][rr], acc[3][rr] };
                __builtin_nontemporal_store(o, (f32x4*)(out + (long)row * NCOLS + col0));
            }
        }
    } else if (gw < NFULL + 2) {  // 32-col tail: 2 waves x 16 cols
        const int tw  = gw - NFULL;
        const int col = NFULL * 64 + tw * 16 + laneN;
        const float* xb = X + col;
        bf16x8 bfrag[2];
#pragma unroll
        for (int q = 0; q < 2; ++q) {
            bf16x8 f;
#pragma unroll
            for (int j = 0; j < 8; ++j)
                f[j] = f2bf(xb[(long)(q * 32 + quad * 8 + j) * NCOLS]);
            bfrag[q] = f;
        }
#pragma unroll
        for (int t = 0; t < 4; ++t) {
            f32x4 a = {0.f, 0.f, 0.f, 0.f};
            a = __builtin_amdgcn_mfma_f32_16x16x32_bf16(afrag[t][0], bfrag[0], a, 0, 0, 0);
            a = __builtin_amdgcn_mfma_f32_16x16x32_bf16(afrag[t][1], bfrag[1], a, 0, 0, 0);
#pragma unroll
            for (int rr = 0; rr < 4; ++rr)
                __builtin_nontemporal_store(a[rr],
                    out + (long)(t * 16 + quad * 4 + rr) * NCOLS + col);
        }
    }
}

extern "C" void kernel_launch(void* const* d_in, const int* in_sizes, int n_in,
                              void* d_out, int out_size, void* d_ws, size_t ws_size,
                              hipStream_t stream) {
    const float* X      = (const float*)d_in[0];
    const float* angles = (const float*)d_in[1];
    const float* mus    = (const float*)d_in[2];
    fused_ortho<<<BLOCKS, TPB, 0, stream>>>(X, angles, mus, (float*)d_out);
}

// Round 6
// 282.390 us; speedup vs baseline: 1.1706x; 1.1706x over previous
//
#include <hip/hip_runtime.h>

#define NPTS   64
#define NCOLS  500000
#define NANG   2016        // 64*63/2
#define NFULL  7812        // NCOLS / 64 (32-col tail = 2 extra 16-col waves)
#define TPB    512         // 8 waves/block
#define BLOCKS 512         // 2 blocks/CU -> 16 waves/CU resident
#define NWAVES (BLOCKS * 8)   // 4096 global waves

typedef __attribute__((ext_vector_type(8))) short bf16x8;
typedef __attribute__((ext_vector_type(4))) float f32x4;

static __device__ __forceinline__ short f2bf(float f) {
    union { float f; unsigned u; } uf; uf.f = f;
    unsigned u = uf.u;
    unsigned r = (u + 0x7fffu + ((u >> 16) & 1u)) >> 16;  // RNE bf16
    return (short)r;
}

// ---------------------------------------------------------------------------
// Register-resident masked Givens chunk: rounds [I0, I1) of the iTop loop.
// q[64] lives in registers with FULLY STATIC indices. Outer loop rolled
// (i is wave-uniform runtime); inner fully unrolled over all 64 rows with
// identity coefficients (c,s)=(1,0) for j<=i -- pass-through is EXACT
// (fma(0,t,1*b)=b). t=q[i] extracted/scattered via uniform cndmask scans.
// csn is the GLOBAL table; index rotS(i)+(j-i-1) = base+j is absolute.
// (Round-5 bug: call sites ALSO offset csn -> waves 1,2 read wrong angles.)
// ---------------------------------------------------------------------------
__device__ __forceinline__ void chunk_reg(const float2* __restrict__ csn,
                                          float* __restrict__ P,
                                          int lane, int I0, int I1) {
    float q[64];
#pragma unroll
    for (int r = 0; r < 64; ++r) q[r] = (r == lane) ? 1.0f : 0.0f;

#pragma unroll 1
    for (int i = I0; i < I1; ++i) {
        // t = q[i] (i wave-uniform -> cndmask scan)
        float t = q[0];
#pragma unroll
        for (int j = 1; j < 64; ++j) t = (j == i) ? q[j] : t;

        // rotation (i,j): global csn index k = rotS(i) + (j-i-1) = base + j
        const int base = 63 * i - (i * (i - 1)) / 2 - i - 1;   // j>=1 -> index >= 0
#pragma unroll
        for (int j = 1; j < 64; ++j) {
            const float2 cs = csn[base + j];      // stale-but-valid read when j<=i
            const bool  act = (j > i);            // uniform
            const float c = act ? cs.x : 1.0f;
            const float s = act ? cs.y : 0.0f;
            const float b = q[j];
            q[j] = fmaf(s, t, c * b);             // vb' = s*vt + c*vb (old vt)
            t    = fmaf(c, t, -(s * b));          // vt' = c*vt - s*vb
        }
        // q[i] = t (uniform scatter)
#pragma unroll
        for (int j = 0; j < 64; ++j) q[j] = (j == i) ? t : q[j];
    }

#pragma unroll
    for (int r = 0; r < 64; ++r) P[r * 64 + lane] = q[r];
}

// ---- streaming helpers (all indices static after inlining) ----
__device__ __forceinline__ void issue8(const float* __restrict__ xb, int kbase,
                                       f32x4 xq[8]) {
#pragma unroll
    for (int j = 0; j < 8; ++j)
        xq[j] = *(const f32x4*)(xb + (long)(kbase + j) * NCOLS);
}

template<int Q>
__device__ __forceinline__ void cvt8(const f32x4 xq[8], bf16x8 bfrag[4][2]) {
#pragma unroll
    for (int j = 0; j < 8; ++j)
#pragma unroll
        for (int u = 0; u < 4; ++u)
            bfrag[u][Q][j] = f2bf(xq[j][u]);
}

__device__ __forceinline__ void mfma_store(const bf16x8 afrag[4][2],
                                           const bf16x8 bfrag[4][2],
                                           float* __restrict__ out, long col0,
                                           int quad) {
#pragma unroll
    for (int t = 0; t < 4; ++t) {
        f32x4 acc[4];
#pragma unroll
        for (int u = 0; u < 4; ++u) {
            f32x4 a = {0.f, 0.f, 0.f, 0.f};
            a = __builtin_amdgcn_mfma_f32_16x16x32_bf16(afrag[t][0], bfrag[u][0], a, 0, 0, 0);
            a = __builtin_amdgcn_mfma_f32_16x16x32_bf16(afrag[t][1], bfrag[u][1], a, 0, 0, 0);
            acc[u] = a;
        }
#pragma unroll
        for (int rr = 0; rr < 4; ++rr) {
            const int row = t * 16 + quad * 4 + rr;
            f32x4 o = { acc[0][rr], acc[1][rr], acc[2][rr], acc[3][rr] };
            __builtin_nontemporal_store(o, (f32x4*)(out + (long)row * NCOLS + col0));
        }
    }
}

// ---------------------------------------------------------------------------
// Single fused kernel (512 thr, 65280B LDS, VGPR target ~120 @ (512,4)):
//   phase 0: cos/sin of 2016 angles -> LDS
//   phase 1: P0=[0,21) P1=[21,42) P2=[42,63) register-chains (waves 0..2);
//            waves 3..7 prefetch their stripe-0 q0 X-loads meanwhile
//   phase 2: Q0 = P1*P0 -> P0 ; M = diag(mus)*P2*Q0 -> P1   (8 waves x 8 rows)
//   phase 3: afrag <- bf16(M); 2 stripes/wave with q0-of-next prefetch
// ---------------------------------------------------------------------------
__global__ __launch_bounds__(TPB, 4) void fused_ortho(const float* __restrict__ X,
                                                      const float* __restrict__ angles,
                                                      const float* __restrict__ mus,
                                                      float* __restrict__ out) {
    __shared__ __align__(16) float sm[4032 + 3 * 4096];   // 65280 B
    const int tid   = threadIdx.x;
    const int lane  = tid & 63;
    const int wave  = __builtin_amdgcn_readfirstlane(tid >> 6);
    const int laneN = lane & 15;
    const int quad  = lane >> 4;

    float2* csn = (float2*)sm;          // 2016 float2 = 16128 B
    float* P0 = sm + 4032;
    float* P1 = sm + 8128;
    float* P2 = sm + 12224;

    const int  gw   = blockIdx.x * 8 + wave;          // [0, 4096)
    const long col0 = (long)gw * 64 + 4 * laneN;      // stripe 0 (always valid)
    f32x4 xq[8];

    // ---- phase 0: stage cos/sin ----
    for (int a = tid; a < NANG; a += TPB) {
        float s, c;
        sincosf(angles[a], &s, &c);
        csn[a] = make_float2(c, s);
    }
    __syncthreads();

    // ---- phase 1: three parallel register chains; other waves prefetch X ----
    // boundaries balanced by ROUND count (cost/round ~constant); csn is the
    // GLOBAL table for all three (indexing inside is absolute).
    if (wave == 0)      chunk_reg(csn, P0, lane,  0, 21);
    else if (wave == 1) chunk_reg(csn, P1, lane, 21, 42);
    else if (wave == 2) chunk_reg(csn, P2, lane, 42, 63);
    else                issue8(X + col0, quad * 8, xq);   // q0(s0) prefetch
    __syncthreads();
    if (wave < 3) issue8(X + col0, quad * 8, xq);         // chain waves: covered by phase 2

    // ---- phase 2a: Q0 = P1 * P0 -> P0 slot (wave owns rows wave*8..+7) ----
    {
        const int row0 = wave * 8;
        float acc[8] = {0.f, 0.f, 0.f, 0.f, 0.f, 0.f, 0.f, 0.f};
#pragma unroll 4
        for (int k0 = 0; k0 < 64; k0 += 4) {
            float lo0 = P0[(k0 + 0) * 64 + lane];
            float lo1 = P0[(k0 + 1) * 64 + lane];
            float lo2 = P0[(k0 + 2) * 64 + lane];
            float lo3 = P0[(k0 + 3) * 64 + lane];
#pragma unroll
            for (int r = 0; r < 8; ++r) {
                const f32x4 h = *(const f32x4*)&P1[(row0 + r) * 64 + k0]; // broadcast
                acc[r] = fmaf(h[0], lo0, acc[r]);
                acc[r] = fmaf(h[1], lo1, acc[r]);
                acc[r] = fmaf(h[2], lo2, acc[r]);
                acc[r] = fmaf(h[3], lo3, acc[r]);
            }
        }
        __syncthreads();               // all P0/P1 reads done before overwrite
#pragma unroll
        for (int r = 0; r < 8; ++r) P0[(row0 + r) * 64 + lane] = acc[r];
    }
    __syncthreads();

    // ---- phase 2b: M = diag(mus) * P2 * Q0 -> P1 slot ----
    {
        const int row0 = wave * 8;
        float acc[8] = {0.f, 0.f, 0.f, 0.f, 0.f, 0.f, 0.f, 0.f};
#pragma unroll 4
        for (int k0 = 0; k0 < 64; k0 += 4) {
            float lo0 = P0[(k0 + 0) * 64 + lane];
            float lo1 = P0[(k0 + 1) * 64 + lane];
            float lo2 = P0[(k0 + 2) * 64 + lane];
            float lo3 = P0[(k0 + 3) * 64 + lane];
#pragma unroll
            for (int r = 0; r < 8; ++r) {
                const f32x4 h = *(const f32x4*)&P2[(row0 + r) * 64 + k0]; // broadcast
                acc[r] = fmaf(h[0], lo0, acc[r]);
                acc[r] = fmaf(h[1], lo1, acc[r]);
                acc[r] = fmaf(h[2], lo2, acc[r]);
                acc[r] = fmaf(h[3], lo3, acc[r]);
            }
        }
        // writes target P1 (not read in this phase)
#pragma unroll
        for (int r = 0; r < 8; ++r)
            P1[(row0 + r) * 64 + lane] = acc[r] * mus[row0 + r];
    }
    __syncthreads();

    // ---- phase 3: afrag from M (P1 slot), then streaming ----
    bf16x8 afrag[4][2];
#pragma unroll
    for (int t = 0; t < 4; ++t) {
#pragma unroll
        for (int q = 0; q < 2; ++q) {
            const float* src = P1 + (t * 16 + laneN) * 64 + q * 32 + quad * 8;
            bf16x8 f;
#pragma unroll
            for (int j = 0; j < 8; ++j) f[j] = f2bf(src[j]);
            afrag[t][q] = f;
        }
    }

    const long s1   = (long)gw + NWAVES;              // second stripe
    const bool has1 = (s1 < NFULL);
    const long col1 = s1 * 64 + 4 * laneN;

    bf16x8 bfrag[4][2];
    // -- stripe 0: xq holds q0(s0), prefetched during setup --
    cvt8<0>(xq, bfrag);
    issue8(X + col0, 32 + quad * 8, xq);              // q1(s0)
    cvt8<1>(xq, bfrag);
    if (has1) issue8(X + col1, quad * 8, xq);         // q0(s1): in flight over MFMA+stores
    mfma_store(afrag, bfrag, out, col0, quad);

    if (has1) {
        cvt8<0>(xq, bfrag);
        issue8(X + col1, 32 + quad * 8, xq);          // q1(s1)
        cvt8<1>(xq, bfrag);
        mfma_store(afrag, bfrag, out, col1, quad);
    }

    if (gw >= NWAVES - 2) {  // 32-col tail: 2 waves x 16 cols
        const int tw  = gw - (NWAVES - 2);
        const int col = NFULL * 64 + tw * 16 + laneN;
        const float* xb = X + col;
        bf16x8 bt[2];
#pragma unroll
        for (int q = 0; q < 2; ++q) {
            bf16x8 f;
#pragma unroll
            for (int j = 0; j < 8; ++j)
                f[j] = f2bf(xb[(long)(q * 32 + quad * 8 + j) * NCOLS]);
            bt[q] = f;
        }
#pragma unroll
        for (int t = 0; t < 4; ++t) {
            f32x4 a = {0.f, 0.f, 0.f, 0.f};
            a = __builtin_amdgcn_mfma_f32_16x16x32_bf16(afrag[t][0], bt[0], a, 0, 0, 0);
            a = __builtin_amdgcn_mfma_f32_16x16x32_bf16(afrag[t][1], bt[1], a, 0, 0, 0);
#pragma unroll
            for (int rr = 0; rr < 4; ++rr)
                __builtin_nontemporal_store(a[rr],
                    out + (long)(t * 16 + quad * 4 + rr) * NCOLS + col);
        }
    }
}

extern "C" void kernel_launch(void* const* d_in, const int* in_sizes, int n_in,
                              void* d_out, int out_size, void* d_ws, size_t ws_size,
                              hipStream_t stream) {
    const float* X      = (const float*)d_in[0];
    const float* angles = (const float*)d_in[1];
    const float* mus    = (const float*)d_in[2];
    fused_ortho<<<BLOCKS, TPB, 0, stream>>>(X, angles, mus, (float*)d_out);
}